// Round 1
// baseline (6242.505 us; speedup 1.0000x reference)
//
#include <hip/hip_runtime.h>
#include <hip/hip_bf16.h>

#define NL 4000
#define NC 8000
#define EMB 128
#define ROWC0 4096          // clause region start (64-aligned)
#define NR (ROWC0 + NC)     // 12096 total rows (multiple of 64)
#define TSTEPS 30
#define LCHUNK 80           // 50 chunks of 80 lits for transpose-CSR build
#define NCHUNK 50

// ---------------------------------------------------------------------------
// Generic row-batched GEMM: C[r][j] = act( sum_k A1[r][k]*Wa[j][k]
//                                        (+ sum_k A2[r][k]*Wb[j][k]) + bias[j] )
// Rows < ROWC0 use the "L" weight set, rows >= ROWC0 use the "C" set.
// 64x64 tile, 256 threads, 4x4 microtile, K-transposed LDS (stride 68).
// ---------------------------------------------------------------------------
template<int K, bool RELU, bool TWOA>
__global__ __launch_bounds__(256) void gemm_rows(
    const float* __restrict__ A1, const float* __restrict__ A2,
    const float* __restrict__ W1l, const float* __restrict__ W1c,
    const float* __restrict__ W2l, const float* __restrict__ W2c,
    const float* __restrict__ bl, const float* __restrict__ bc,
    float* __restrict__ Cout, int F)
{
    const int row0 = blockIdx.y * 64;
    const bool isC = (row0 >= ROWC0);
    const float* Wa = isC ? W1c : W1l;
    const float* Wb = TWOA ? (isC ? W2c : W2l) : nullptr;
    const float* bias = isC ? bc : bl;
    const int j0 = blockIdx.x * 64;
    const int t = threadIdx.x;
    const int tx = t & 15, ty = t >> 4;

    __shared__ float As[32][68];
    __shared__ float Ws[32][68];

    float acc[4][4];
#pragma unroll
    for (int i = 0; i < 4; ++i)
#pragma unroll
        for (int j = 0; j < 4; ++j) acc[i][j] = 0.f;

    const int nph = TWOA ? 2 : 1;
    for (int ph = 0; ph < nph; ++ph) {
        const float* A = ph ? A2 : A1;
        const float* W = ph ? Wb : Wa;
        for (int kc = 0; kc < K; kc += 32) {
#pragma unroll
            for (int q = 0; q < 2; ++q) {
                int f4 = t + q * 256;       // 0..511
                int r = f4 >> 3;            // 0..63
                int k4 = (f4 & 7) * 4;      // 0..28
                int k = kc + k4;
                float4 v = make_float4(0.f, 0.f, 0.f, 0.f);
                if (k < K) v = *(const float4*)&A[(size_t)(row0 + r) * K + k];
                As[k4 + 0][r] = v.x; As[k4 + 1][r] = v.y;
                As[k4 + 2][r] = v.z; As[k4 + 3][r] = v.w;
                int jr = j0 + r;
                float4 w = make_float4(0.f, 0.f, 0.f, 0.f);
                if (k < K && jr < F) w = *(const float4*)&W[(size_t)jr * K + k];
                Ws[k4 + 0][r] = w.x; Ws[k4 + 1][r] = w.y;
                Ws[k4 + 2][r] = w.z; Ws[k4 + 3][r] = w.w;
            }
            __syncthreads();
#pragma unroll
            for (int kk = 0; kk < 32; ++kk) {
                float4 a = *(const float4*)&As[kk][ty * 4];
                float4 w = *(const float4*)&Ws[kk][tx * 4];
                float av[4] = {a.x, a.y, a.z, a.w};
                float wv[4] = {w.x, w.y, w.z, w.w};
#pragma unroll
                for (int i = 0; i < 4; ++i)
#pragma unroll
                    for (int j = 0; j < 4; ++j) acc[i][j] += av[i] * wv[j];
            }
            __syncthreads();
        }
    }

    int jj = j0 + tx * 4;
    if (jj < F) {
        float4 bv = *(const float4*)&bias[jj];
#pragma unroll
        for (int i = 0; i < 4; ++i) {
            int r = row0 + ty * 4 + i;
            float4 o;
            o.x = acc[i][0] + bv.x; o.y = acc[i][1] + bv.y;
            o.z = acc[i][2] + bv.z; o.w = acc[i][3] + bv.w;
            if (RELU) {
                o.x = fmaxf(o.x, 0.f); o.y = fmaxf(o.y, 0.f);
                o.z = fmaxf(o.z, 0.f); o.w = fmaxf(o.w, 0.f);
            }
            *(float4*)&Cout[(size_t)r * F + jj] = o;
        }
    }
}

// ---------------------------------------------------------------------------
// SpMM: msgs gather-sum (M is binary, so no multiplies).
// out rows < NL: lit row l sums Xmsg[ROWC0+c] over clause list.
// out rows >= ROWC0: clause row c sums Xmsg[l] over lit list.
// 2 rows per block (128 threads each = 2 waves per row).
// ---------------------------------------------------------------------------
__global__ __launch_bounds__(256) void spmm_kernel(
    const int* __restrict__ Lp, const int* __restrict__ Li,
    const int* __restrict__ Tp, const int* __restrict__ Ti,
    const float* __restrict__ X, float* __restrict__ out)
{
    const int r = blockIdx.x * 2 + (threadIdx.x >> 7);
    const int col = threadIdx.x & 127;
    if (r >= NR) return;
    float s = 0.f;
    if (r < NL) {
        int b = Lp[r], e = Lp[r + 1];
        int i = b;
        for (; i + 3 < e; i += 4) {
            int c0 = Li[i], c1 = Li[i + 1], c2 = Li[i + 2], c3 = Li[i + 3];
            s += X[(size_t)(ROWC0 + c0) * EMB + col];
            s += X[(size_t)(ROWC0 + c1) * EMB + col];
            s += X[(size_t)(ROWC0 + c2) * EMB + col];
            s += X[(size_t)(ROWC0 + c3) * EMB + col];
        }
        for (; i < e; ++i) s += X[(size_t)(ROWC0 + Li[i]) * EMB + col];
    } else if (r >= ROWC0) {
        int c = r - ROWC0;
        int b = Tp[c], e = Tp[c + 1];
        int i = b;
        for (; i + 3 < e; i += 4) {
            int l0 = Ti[i], l1 = Ti[i + 1], l2 = Ti[i + 2], l3 = Ti[i + 3];
            s += X[(size_t)l0 * EMB + col];
            s += X[(size_t)l1 * EMB + col];
            s += X[(size_t)l2 * EMB + col];
            s += X[(size_t)l3 * EMB + col];
        }
        for (; i < e; ++i) s += X[(size_t)Ti[i] * EMB + col];
    }
    out[(size_t)r * EMB + col] = s;
}

// ---------------------------------------------------------------------------
// LSTM elementwise: gates [NR][512] layout i|f|g|o.
// ---------------------------------------------------------------------------
__device__ __forceinline__ float sigf(float x) { return 1.f / (1.f + expf(-x)); }

__global__ __launch_bounds__(256) void lstm_elem(
    const float* __restrict__ gates, const float* __restrict__ Cold,
    float* __restrict__ Hnew, float* __restrict__ Cnew)
{
    size_t idx = (size_t)blockIdx.x * 256 + threadIdx.x;
    if (idx >= (size_t)NR * EMB) return;
    int r = (int)(idx >> 7);
    int e = (int)(idx & 127);
    const float* g = &gates[(size_t)r * 512];
    float gi = g[e], gf = g[e + 128], gg = g[e + 256], go = g[e + 384];
    float c = Cold[idx];
    float c2 = sigf(gf) * c + sigf(gi) * tanhf(gg);
    float h2 = sigf(go) * tanhf(c2);
    Hnew[idx] = h2;
    Cnew[idx] = c2;
}

// ---------------------------------------------------------------------------
// State init: Lh rows = L_init, clause rows = C_init, pads zero; cell = 0.
// ---------------------------------------------------------------------------
__global__ __launch_bounds__(256) void init_states(
    const float* __restrict__ Li, const float* __restrict__ Ci,
    float* __restrict__ H, float* __restrict__ C, float* __restrict__ accum)
{
    size_t idx = (size_t)blockIdx.x * 256 + threadIdx.x;
    if (idx >= (size_t)NR * EMB) return;
    int r = (int)(idx >> 7);
    int e = (int)(idx & 127);
    float h = 0.f;
    if (r < NL) h = Li[e];
    else if (r >= ROWC0) h = Ci[e];
    H[idx] = h;
    C[idx] = 0.f;
    if (idx == 0) accum[0] = 0.f;
}

// ---------------------------------------------------------------------------
// CSR build (deterministic, ascending index order in every list)
// ---------------------------------------------------------------------------
__global__ __launch_bounds__(256) void count_rows_L(const float* __restrict__ M, int* __restrict__ cnt)
{
    int l = blockIdx.x, t = threadIdx.x;
    int c_ = 0;
    for (int c = t; c < NC; c += 256) c_ += (M[(size_t)l * NC + c] != 0.f) ? 1 : 0;
#pragma unroll
    for (int off = 32; off > 0; off >>= 1) c_ += __shfl_down(c_, off);
    __shared__ int w[4];
    if ((t & 63) == 0) w[t >> 6] = c_;
    __syncthreads();
    if (t == 0) cnt[l] = w[0] + w[1] + w[2] + w[3];
}

__global__ __launch_bounds__(256) void scan_excl(const int* __restrict__ in, int* __restrict__ out, int n)
{
    const int t = threadIdx.x;
    const int per = (n + 255) >> 8;
    __shared__ int part[256];
    int s = 0;
    const int start = t * per;
    for (int i = 0; i < per; ++i) { int idx = start + i; if (idx < n) s += in[idx]; }
    part[t] = s;
    __syncthreads();
    for (int off = 1; off < 256; off <<= 1) {
        int v = (t >= off) ? part[t - off] : 0;
        __syncthreads();
        part[t] += v;
        __syncthreads();
    }
    int run = (t == 0) ? 0 : part[t - 1];
    for (int i = 0; i < per; ++i) {
        int idx = start + i;
        if (idx < n) { out[idx] = run; run += in[idx]; }
    }
    if (t == 255) out[n] = part[255];
}

__global__ __launch_bounds__(256) void fill_L(const float* __restrict__ M,
                                              const int* __restrict__ Lp, int* __restrict__ Lidx)
{
    int l = blockIdx.x, t = threadIdx.x, lane = t & 63, wid = t >> 6;
    __shared__ int wcnt[4];
    __shared__ int base;
    if (t == 0) base = Lp[l];
    __syncthreads();
    for (int c0 = 0; c0 < NC; c0 += 256) {
        int c = c0 + t;
        bool p = (c < NC) && (M[(size_t)l * NC + c] != 0.f);
        unsigned long long m = __ballot(p);
        if (lane == 0) wcnt[wid] = (int)__popcll(m);
        __syncthreads();
        int off = base;
        for (int w = 0; w < wid; ++w) off += wcnt[w];
        int rank = (int)__popcll(m & ((1ull << lane) - 1ull));
        if (p) Lidx[off + rank] = c;
        __syncthreads();
        if (t == 0) base += wcnt[0] + wcnt[1] + wcnt[2] + wcnt[3];
        __syncthreads();
    }
}

__global__ __launch_bounds__(256) void count_T(const float* __restrict__ M, int* __restrict__ cnt2d)
{
    int s = blockIdx.y;
    int c = blockIdx.x * 256 + threadIdx.x;
    if (c >= NC) return;
    int n = 0;
    int l0 = s * LCHUNK, l1 = l0 + LCHUNK;
    for (int l = l0; l < l1; ++l) n += (M[(size_t)l * NC + c] != 0.f) ? 1 : 0;
    cnt2d[(size_t)s * NC + c] = n;
}

__global__ __launch_bounds__(256) void colscan_T(const int* __restrict__ cnt2d,
                                                 int* __restrict__ cum2d, int* __restrict__ cntT)
{
    int c = blockIdx.x * 256 + threadIdx.x;
    if (c >= NC) return;
    int run = 0;
    for (int s = 0; s < NCHUNK; ++s) {
        cum2d[(size_t)s * NC + c] = run;
        run += cnt2d[(size_t)s * NC + c];
    }
    cntT[c] = run;
}

__global__ __launch_bounds__(256) void fill_T(const float* __restrict__ M,
                                              const int* __restrict__ Tp, const int* __restrict__ cum2d,
                                              int* __restrict__ Tidx)
{
    int s = blockIdx.y;
    int c = blockIdx.x * 256 + threadIdx.x;
    if (c >= NC) return;
    int pos = Tp[c] + cum2d[(size_t)s * NC + c];
    int l0 = s * LCHUNK, l1 = l0 + LCHUNK;
    for (int l = l0; l < l1; ++l) {
        if (M[(size_t)l * NC + c] != 0.f) Tidx[pos++] = l;
    }
}

// ---------------------------------------------------------------------------
// Vote epilogue: dot each lit row's H2 with V_W3, sigmoid, sum via atomics.
// ---------------------------------------------------------------------------
__global__ __launch_bounds__(256) void vote_reduce(
    const float* __restrict__ H2v, const float* __restrict__ W3,
    const float* __restrict__ b3, float* __restrict__ accum)
{
    int wid = threadIdx.x >> 6, lane = threadIdx.x & 63;
    int r = blockIdx.x * 4 + wid;
    float s = 0.f;
    if (r < NL) {
        const float* x = &H2v[(size_t)r * 200];
        for (int k = lane; k < 200; k += 64) s += x[k] * W3[k];
    }
#pragma unroll
    for (int off = 32; off > 0; off >>= 1) s += __shfl_down(s, off);
    if (lane == 0 && r < NL) {
        float v = 1.f / (1.f + expf(-(s + b3[0])));
        atomicAdd(accum, v);
    }
}

__global__ void finalize_logit(const float* __restrict__ accum, float* __restrict__ out)
{
    float avg = accum[0] / (float)NL;
    out[0] = logf(avg / (1.f - avg));
}

// ---------------------------------------------------------------------------
// Host launcher
// ---------------------------------------------------------------------------
extern "C" void kernel_launch(void* const* d_in, const int* in_sizes, int n_in,
                              void* d_out, int out_size, void* d_ws, size_t ws_size,
                              hipStream_t stream)
{
    const float* M      = (const float*)d_in[0];
    const float* L_init = (const float*)d_in[1];
    const float* C_init = (const float*)d_in[2];
    const float* LC_W1 = (const float*)d_in[3];  const float* LC_b1 = (const float*)d_in[4];
    const float* LC_W2 = (const float*)d_in[5];  const float* LC_b2 = (const float*)d_in[6];
    const float* LC_W3 = (const float*)d_in[7];  const float* LC_b3 = (const float*)d_in[8];
    const float* CL_W1 = (const float*)d_in[9];  const float* CL_b1 = (const float*)d_in[10];
    const float* CL_W2 = (const float*)d_in[11]; const float* CL_b2 = (const float*)d_in[12];
    const float* CL_W3 = (const float*)d_in[13]; const float* CL_b3 = (const float*)d_in[14];
    const float* L_Wih = (const float*)d_in[15]; const float* L_Whh = (const float*)d_in[16];
    const float* L_b   = (const float*)d_in[17];
    const float* C_Wih = (const float*)d_in[18]; const float* C_Whh = (const float*)d_in[19];
    const float* C_b   = (const float*)d_in[20];
    const float* V_W1 = (const float*)d_in[21]; const float* V_b1 = (const float*)d_in[22];
    const float* V_W2 = (const float*)d_in[23]; const float* V_b2 = (const float*)d_in[24];
    const float* V_W3 = (const float*)d_in[25]; const float* V_b3 = (const float*)d_in[26];
    float* out = (float*)d_out;

    // workspace sub-allocation (256B aligned)
    char* ws = (char*)d_ws;
    size_t off = 0;
    auto alloc = [&](size_t bytes) -> void* {
        void* p = ws + off;
        off += (bytes + 255) & ~(size_t)255;
        return p;
    };
    float* HA   = (float*)alloc((size_t)NR * EMB * 4);
    float* CA   = (float*)alloc((size_t)NR * EMB * 4);
    float* HB   = (float*)alloc((size_t)NR * EMB * 4);
    float* CB   = (float*)alloc((size_t)NR * EMB * 4);
    float* msgs = (float*)alloc((size_t)NR * EMB * 4);
    float* Xmsg = (float*)alloc((size_t)NR * EMB * 4);
    float* H1g  = (float*)alloc((size_t)NR * 512 * 4);   // H1 (stride 400) and gates (stride 512)
    float* H2b  = (float*)alloc((size_t)NR * 200 * 4);
    float* accum = (float*)alloc(256);
    int* Lp   = (int*)alloc(4104 * 4);
    int* Tp   = (int*)alloc(8104 * 4);
    int* Lidx = (int*)alloc(1000000 * 4);
    int* Tidx = (int*)alloc(1000000 * 4);
    int* cnt2d = (int*)alloc((size_t)NCHUNK * NC * 4);
    int* cum2d = (int*)alloc((size_t)NCHUNK * NC * 4);
    int* cntL = (int*)alloc(4096 * 4);
    int* cntT = (int*)alloc(8192 * 4);
    (void)ws_size; (void)in_sizes; (void)n_in; (void)out_size;

    // --- CSR build ---
    count_rows_L<<<NL, 256, 0, stream>>>(M, cntL);
    scan_excl<<<1, 256, 0, stream>>>(cntL, Lp, NL);
    fill_L<<<NL, 256, 0, stream>>>(M, Lp, Lidx);
    {
        dim3 g((NC + 255) / 256, NCHUNK);
        count_T<<<g, 256, 0, stream>>>(M, cnt2d);
        colscan_T<<<(NC + 255) / 256, 256, 0, stream>>>(cnt2d, cum2d, cntT);
        scan_excl<<<1, 256, 0, stream>>>(cntT, Tp, NC);
        fill_T<<<g, 256, 0, stream>>>(M, Tp, cum2d, Tidx);
    }

    // --- init ---
    const int nelem_blocks = (NR * EMB + 255) / 256;
    init_states<<<nelem_blocks, 256, 0, stream>>>(L_init, C_init, HA, CA, accum);

    // --- 30 message-passing steps ---
    float* Hcur = HA; float* Ccur = CA;
    float* Hnxt = HB; float* Cnxt = CB;
    const int RT = NR / 64;  // 189 row tiles
    for (int step = 0; step < TSTEPS; ++step) {
        gemm_rows<128, true, false><<<dim3(7, RT), 256, 0, stream>>>(
            Hcur, nullptr, LC_W1, CL_W1, nullptr, nullptr, LC_b1, CL_b1, H1g, 400);
        gemm_rows<400, true, false><<<dim3(4, RT), 256, 0, stream>>>(
            H1g, nullptr, LC_W2, CL_W2, nullptr, nullptr, LC_b2, CL_b2, H2b, 200);
        gemm_rows<200, false, false><<<dim3(2, RT), 256, 0, stream>>>(
            H2b, nullptr, LC_W3, CL_W3, nullptr, nullptr, LC_b3, CL_b3, Xmsg, 128);
        spmm_kernel<<<NR / 2, 256, 0, stream>>>(Lp, Lidx, Tp, Tidx, Xmsg, msgs);
        gemm_rows<128, false, true><<<dim3(8, RT), 256, 0, stream>>>(
            msgs, Hcur, L_Wih, C_Wih, L_Whh, C_Whh, L_b, C_b, H1g, 512);
        lstm_elem<<<nelem_blocks, 256, 0, stream>>>(H1g, Ccur, Hnxt, Cnxt);
        float* th = Hcur; Hcur = Hnxt; Hnxt = th;
        float* tc = Ccur; Ccur = Cnxt; Cnxt = tc;
    }

    // --- vote MLP + logit ---
    gemm_rows<128, true, false><<<dim3(7, 64), 256, 0, stream>>>(
        Hcur, nullptr, V_W1, V_W1, nullptr, nullptr, V_b1, V_b1, H1g, 400);
    gemm_rows<400, true, false><<<dim3(4, 64), 256, 0, stream>>>(
        H1g, nullptr, V_W2, V_W2, nullptr, nullptr, V_b2, V_b2, H2b, 200);
    vote_reduce<<<(NL + 3) / 4, 256, 0, stream>>>(H2b, V_W3, V_b3, accum);
    finalize_logit<<<1, 1, 0, stream>>>(accum, out);
}

// Round 2
// 5030.575 us; speedup vs baseline: 1.2409x; 1.2409x over previous
//
#include <hip/hip_runtime.h>

#define NL 4000
#define NC 8000
#define EMB 128
#define ROWC0 4096           // clause region start
#define NRP 12288            // padded total rows (48 x 256)
#define NRREAL (ROWC0 + NC)  // 12096 rows with data
#define TSTEPS 30
#define LCHUNK 80
#define NCHUNK 50
#define BM 256
#define BN 64

typedef __attribute__((ext_vector_type(8))) short bf16x8;
typedef __attribute__((ext_vector_type(4))) float f32x4;

__device__ __forceinline__ short f2bf(float x) {
    union { float f; unsigned u; } v; v.f = x;
    unsigned r = v.u + 0x7fffu + ((v.u >> 16) & 1u);
    return (short)(r >> 16);
}
__device__ __forceinline__ float bf2f(short s) {
    union { unsigned u; float f; } v; v.u = ((unsigned)(unsigned short)s) << 16;
    return v.f;
}

__device__ __forceinline__ void gload16(const void* g, void* l) {
    __builtin_amdgcn_global_load_lds(
        (const __attribute__((address_space(1))) unsigned int*)g,
        (__attribute__((address_space(3))) unsigned int*)l, 16, 0, 0);
}

// ---------------------------------------------------------------------------
// Split-bf16 MFMA GEMM. Out[r][f] = act( sum_k A[r][k] * W[f][k] + bias[f] )
// A, W given as hi/lo bf16 pairs; product = Ah*Wh + Ah*Wl + Al*Wh (fp32 acc).
// Block: 256 thr = 4 waves; tile BM=256 rows x BN=64 cols; wave: 64x64.
// LDS tiles [rows][32k] bf16, XOR-swizzled: lds_off = row*64 + (slot ^ ((row>>1)&3))*16.
// Rows < ROWC0 use the L weight set, rows >= ROWC0 the C set.
// ---------------------------------------------------------------------------
template<int KS, bool TWOA, bool RELU, bool OUT_SPLIT>
__global__ __launch_bounds__(256) void mfma_gemm(
    const short* __restrict__ A1h, const short* __restrict__ A1l,
    const short* __restrict__ A2h, const short* __restrict__ A2l,
    const short* __restrict__ W1hL, const short* __restrict__ W1lL,
    const short* __restrict__ W1hC, const short* __restrict__ W1lC,
    const short* __restrict__ W2hL, const short* __restrict__ W2lL,
    const short* __restrict__ W2hC, const short* __restrict__ W2lC,
    const float* __restrict__ biasL, const float* __restrict__ biasC,
    short* __restrict__ OutH, short* __restrict__ OutL, float* __restrict__ OutF,
    int Freal, int Fstore)
{
    __shared__ short sAh[BM * 32];
    __shared__ short sAl[BM * 32];
    __shared__ short sBh[BN * 32];
    __shared__ short sBl[BN * 32];

    const int row0 = blockIdx.y * BM;
    const int c0 = blockIdx.x * BN;
    const bool isC = (row0 >= ROWC0);
    const int t = threadIdx.x;
    const int lane = t & 63;
    const int w = t >> 6;

    f32x4 acc[4][4] = {};

    const int nph = TWOA ? 2 : 1;
    for (int ph = 0; ph < nph; ++ph) {
        const short* Ah = (TWOA && ph) ? A2h : A1h;
        const short* Al = (TWOA && ph) ? A2l : A1l;
        const short* Bh = (TWOA && ph) ? (isC ? W2hC : W2hL) : (isC ? W1hC : W1hL);
        const short* Bl = (TWOA && ph) ? (isC ? W2lC : W2lL) : (isC ? W1lC : W1lL);

        for (int kc = 0; kc < KS; kc += 32) {
            // ---- stage A tile (16KB per split): 4 issues per wave per split
#pragma unroll
            for (int q = 0; q < 4; ++q) {
                int o = w * 4096 + q * 1024 + lane * 16;   // linear LDS byte offset
                int row = o >> 6;
                int slot = (o >> 4) & 3;
                int gk = kc + (((slot ^ ((row >> 1) & 3))) << 3);
                size_t gi = (size_t)(row0 + row) * KS + gk;
                gload16(&Ah[gi], ((char*)sAh) + o);
                gload16(&Al[gi], ((char*)sAl) + o);
            }
            // ---- stage B tile (4KB per split): 1 issue per thread per split
            {
                int o = t * 16;
                int row = o >> 6;                 // weight row (= out col) 0..63
                int slot = (o >> 4) & 3;
                int gk = kc + (((slot ^ ((row >> 1) & 3))) << 3);
                size_t gi = (size_t)(c0 + row) * KS + gk;
                gload16(&Bh[gi], ((char*)sBh) + o);
                gload16(&Bl[gi], ((char*)sBl) + o);
            }
            __syncthreads();   // drains vmcnt (global_load_lds) + lgkm

            bf16x8 af[4][2], bfr[4][2];
#pragma unroll
            for (int s = 0; s < 4; ++s) {
                int row = w * 64 + s * 16 + (lane & 15);
                int slot = (lane >> 4) ^ ((row >> 1) & 3);
                int idx = row * 32 + slot * 8;
                af[s][0] = *(const bf16x8*)&sAh[idx];
                af[s][1] = *(const bf16x8*)&sAl[idx];
                int colr = s * 16 + (lane & 15);
                int slotb = (lane >> 4) ^ ((colr >> 1) & 3);
                int idxb = colr * 32 + slotb * 8;
                bfr[s][0] = *(const bf16x8*)&sBh[idxb];
                bfr[s][1] = *(const bf16x8*)&sBl[idxb];
            }
#pragma unroll
            for (int s = 0; s < 4; ++s)
#pragma unroll
                for (int u = 0; u < 4; ++u) {
                    acc[s][u] = __builtin_amdgcn_mfma_f32_16x16x32_bf16(af[s][0], bfr[u][0], acc[s][u], 0, 0, 0);
                    acc[s][u] = __builtin_amdgcn_mfma_f32_16x16x32_bf16(af[s][0], bfr[u][1], acc[s][u], 0, 0, 0);
                    acc[s][u] = __builtin_amdgcn_mfma_f32_16x16x32_bf16(af[s][1], bfr[u][0], acc[s][u], 0, 0, 0);
                }
            __syncthreads();
        }
    }

    // ---- epilogue: C/D frag layout col=lane&15, row=(lane>>4)*4+j (m89)
#pragma unroll
    for (int u = 0; u < 4; ++u) {
        int col = c0 + u * 16 + (lane & 15);
        if (col >= Fstore) continue;
        float bv = (col < Freal) ? (isC ? biasC[col] : biasL[col]) : 0.f;
#pragma unroll
        for (int s = 0; s < 4; ++s) {
#pragma unroll
            for (int j = 0; j < 4; ++j) {
                int row = row0 + w * 64 + s * 16 + (lane >> 4) * 4 + j;
                float v = acc[s][u][j] + bv;
                if (RELU) v = fmaxf(v, 0.f);
                size_t oi = (size_t)row * Fstore + col;
                if (OUT_SPLIT) {
                    short h = f2bf(v);
                    OutH[oi] = h;
                    OutL[oi] = f2bf(v - bf2f(h));
                } else {
                    OutF[oi] = v;
                }
            }
        }
    }
}

// ---------------------------------------------------------------------------
// Weight prep: zero-padded split into hi/lo bf16.
// ---------------------------------------------------------------------------
__global__ __launch_bounds__(256) void split_pad(
    const float* __restrict__ W, short* __restrict__ Wh, short* __restrict__ Wl,
    int rows, int cols, int prows, int pcols)
{
    int i = blockIdx.x * 256 + threadIdx.x;
    if (i >= prows * pcols) return;
    int r = i / pcols, c = i - r * pcols;
    float v = (r < rows && c < cols) ? W[(size_t)r * cols + c] : 0.f;
    short h = f2bf(v);
    Wh[i] = h;
    Wl[i] = f2bf(v - bf2f(h));
}

// ---------------------------------------------------------------------------
// SpMM gather (fp32 in, split-bf16 out).
// ---------------------------------------------------------------------------
__global__ __launch_bounds__(256) void spmm_kernel(
    const int* __restrict__ Lp, const int* __restrict__ Li,
    const int* __restrict__ Tp, const int* __restrict__ Ti,
    const float* __restrict__ X, short* __restrict__ outH, short* __restrict__ outL)
{
    const int r = blockIdx.x * 2 + (threadIdx.x >> 7);
    const int col = threadIdx.x & 127;
    if (r >= NRREAL) return;
    float s = 0.f;
    if (r < NL) {
        int b = Lp[r], e = Lp[r + 1];
        int i = b;
        for (; i + 3 < e; i += 4) {
            s += X[(size_t)(ROWC0 + Li[i]) * EMB + col];
            s += X[(size_t)(ROWC0 + Li[i + 1]) * EMB + col];
            s += X[(size_t)(ROWC0 + Li[i + 2]) * EMB + col];
            s += X[(size_t)(ROWC0 + Li[i + 3]) * EMB + col];
        }
        for (; i < e; ++i) s += X[(size_t)(ROWC0 + Li[i]) * EMB + col];
    } else if (r >= ROWC0) {
        int c = r - ROWC0;
        int b = Tp[c], e = Tp[c + 1];
        int i = b;
        for (; i + 3 < e; i += 4) {
            s += X[(size_t)Ti[i] * EMB + col];
            s += X[(size_t)Ti[i + 1] * EMB + col];
            s += X[(size_t)Ti[i + 2] * EMB + col];
            s += X[(size_t)Ti[i + 3] * EMB + col];
        }
        for (; i < e; ++i) s += X[(size_t)Ti[i] * EMB + col];
    }
    size_t oi = (size_t)r * EMB + col;
    short h = f2bf(s);
    outH[oi] = h;
    outL[oi] = f2bf(s - bf2f(h));
}

// ---------------------------------------------------------------------------
// LSTM elementwise: gates [NRP][512] (i|f|g|o) -> split H, fp32 C.
// ---------------------------------------------------------------------------
__device__ __forceinline__ float sigf(float x) { return 1.f / (1.f + expf(-x)); }

__global__ __launch_bounds__(256) void lstm_elem(
    const float* __restrict__ gates, const float* __restrict__ Cold,
    short* __restrict__ Hh, short* __restrict__ Hl, float* __restrict__ Cnew)
{
    size_t idx = (size_t)blockIdx.x * 256 + threadIdx.x;
    if (idx >= (size_t)NRP * EMB) return;
    int r = (int)(idx >> 7);
    int e = (int)(idx & 127);
    const float* g = &gates[(size_t)r * 512];
    float gi = g[e], gf = g[e + 128], gg = g[e + 256], go = g[e + 384];
    float c2 = sigf(gf) * Cold[idx] + sigf(gi) * tanhf(gg);
    float h2 = sigf(go) * tanhf(c2);
    short h = f2bf(h2);
    Hh[idx] = h;
    Hl[idx] = f2bf(h2 - bf2f(h));
    Cnew[idx] = c2;
}

__global__ __launch_bounds__(256) void init_states(
    const float* __restrict__ Li, const float* __restrict__ Ci,
    short* __restrict__ Hh, short* __restrict__ Hl, float* __restrict__ C,
    float* __restrict__ accum)
{
    size_t idx = (size_t)blockIdx.x * 256 + threadIdx.x;
    if (idx >= (size_t)NRP * EMB) return;
    int r = (int)(idx >> 7);
    int e = (int)(idx & 127);
    float h = 0.f;
    if (r < NL) h = Li[e];
    else if (r >= ROWC0 && r < ROWC0 + NC) h = Ci[e];
    short hh = f2bf(h);
    Hh[idx] = hh;
    Hl[idx] = f2bf(h - bf2f(hh));
    C[idx] = 0.f;
    if (idx == 0) accum[0] = 0.f;
}

// ---------------------------------------------------------------------------
// CSR build (unchanged from round 1 — verified)
// ---------------------------------------------------------------------------
__global__ __launch_bounds__(256) void count_rows_L(const float* __restrict__ M, int* __restrict__ cnt)
{
    int l = blockIdx.x, t = threadIdx.x;
    int c_ = 0;
    for (int c = t; c < NC; c += 256) c_ += (M[(size_t)l * NC + c] != 0.f) ? 1 : 0;
#pragma unroll
    for (int off = 32; off > 0; off >>= 1) c_ += __shfl_down(c_, off);
    __shared__ int w[4];
    if ((t & 63) == 0) w[t >> 6] = c_;
    __syncthreads();
    if (t == 0) cnt[l] = w[0] + w[1] + w[2] + w[3];
}

__global__ __launch_bounds__(256) void scan_excl(const int* __restrict__ in, int* __restrict__ out, int n)
{
    const int t = threadIdx.x;
    const int per = (n + 255) >> 8;
    __shared__ int part[256];
    int s = 0;
    const int start = t * per;
    for (int i = 0; i < per; ++i) { int idx = start + i; if (idx < n) s += in[idx]; }
    part[t] = s;
    __syncthreads();
    for (int off = 1; off < 256; off <<= 1) {
        int v = (t >= off) ? part[t - off] : 0;
        __syncthreads();
        part[t] += v;
        __syncthreads();
    }
    int run = (t == 0) ? 0 : part[t - 1];
    for (int i = 0; i < per; ++i) {
        int idx = start + i;
        if (idx < n) { out[idx] = run; run += in[idx]; }
    }
    if (t == 255) out[n] = part[255];
}

__global__ __launch_bounds__(256) void fill_L(const float* __restrict__ M,
                                              const int* __restrict__ Lp, int* __restrict__ Lidx)
{
    int l = blockIdx.x, t = threadIdx.x, lane = t & 63, wid = t >> 6;
    __shared__ int wcnt[4];
    __shared__ int base;
    if (t == 0) base = Lp[l];
    __syncthreads();
    for (int c0 = 0; c0 < NC; c0 += 256) {
        int c = c0 + t;
        bool p = (c < NC) && (M[(size_t)l * NC + c] != 0.f);
        unsigned long long m = __ballot(p);
        if (lane == 0) wcnt[wid] = (int)__popcll(m);
        __syncthreads();
        int off = base;
        for (int w = 0; w < wid; ++w) off += wcnt[w];
        int rank = (int)__popcll(m & ((1ull << lane) - 1ull));
        if (p) Lidx[off + rank] = c;
        __syncthreads();
        if (t == 0) base += wcnt[0] + wcnt[1] + wcnt[2] + wcnt[3];
        __syncthreads();
    }
}

__global__ __launch_bounds__(256) void count_T(const float* __restrict__ M, int* __restrict__ cnt2d)
{
    int s = blockIdx.y;
    int c = blockIdx.x * 256 + threadIdx.x;
    if (c >= NC) return;
    int n = 0;
    int l0 = s * LCHUNK, l1 = l0 + LCHUNK;
    for (int l = l0; l < l1; ++l) n += (M[(size_t)l * NC + c] != 0.f) ? 1 : 0;
    cnt2d[(size_t)s * NC + c] = n;
}

__global__ __launch_bounds__(256) void colscan_T(const int* __restrict__ cnt2d,
                                                 int* __restrict__ cum2d, int* __restrict__ cntT)
{
    int c = blockIdx.x * 256 + threadIdx.x;
    if (c >= NC) return;
    int run = 0;
    for (int s = 0; s < NCHUNK; ++s) {
        cum2d[(size_t)s * NC + c] = run;
        run += cnt2d[(size_t)s * NC + c];
    }
    cntT[c] = run;
}

__global__ __launch_bounds__(256) void fill_T(const float* __restrict__ M,
                                              const int* __restrict__ Tp, const int* __restrict__ cum2d,
                                              int* __restrict__ Tidx)
{
    int s = blockIdx.y;
    int c = blockIdx.x * 256 + threadIdx.x;
    if (c >= NC) return;
    int pos = Tp[c] + cum2d[(size_t)s * NC + c];
    int l0 = s * LCHUNK, l1 = l0 + LCHUNK;
    for (int l = l0; l < l1; ++l) {
        if (M[(size_t)l * NC + c] != 0.f) Tidx[pos++] = l;
    }
}

// ---------------------------------------------------------------------------
// Vote epilogue
// ---------------------------------------------------------------------------
__global__ __launch_bounds__(256) void vote_reduce(
    const short* __restrict__ H2h, const short* __restrict__ H2l,
    const float* __restrict__ W3, const float* __restrict__ b3, float* __restrict__ accum)
{
    int wid = threadIdx.x >> 6, lane = threadIdx.x & 63;
    int r = blockIdx.x * 4 + wid;
    float s = 0.f;
    if (r < NL) {
        const short* xh = &H2h[(size_t)r * 224];
        const short* xl = &H2l[(size_t)r * 224];
        for (int k = lane; k < 200; k += 64) s += (bf2f(xh[k]) + bf2f(xl[k])) * W3[k];
    }
#pragma unroll
    for (int off = 32; off > 0; off >>= 1) s += __shfl_down(s, off);
    if (lane == 0 && r < NL) {
        float v = 1.f / (1.f + expf(-(s + b3[0])));
        atomicAdd(accum, v);
    }
}

__global__ void finalize_logit(const float* __restrict__ accum, float* __restrict__ out)
{
    float avg = accum[0] / (float)NL;
    out[0] = logf(avg / (1.f - avg));
}

// ---------------------------------------------------------------------------
// Host launcher
// ---------------------------------------------------------------------------
extern "C" void kernel_launch(void* const* d_in, const int* in_sizes, int n_in,
                              void* d_out, int out_size, void* d_ws, size_t ws_size,
                              hipStream_t stream)
{
    const float* M      = (const float*)d_in[0];
    const float* L_init = (const float*)d_in[1];
    const float* C_init = (const float*)d_in[2];
    const float* LC_W1 = (const float*)d_in[3];  const float* LC_b1 = (const float*)d_in[4];
    const float* LC_W2 = (const float*)d_in[5];  const float* LC_b2 = (const float*)d_in[6];
    const float* LC_W3 = (const float*)d_in[7];  const float* LC_b3 = (const float*)d_in[8];
    const float* CL_W1 = (const float*)d_in[9];  const float* CL_b1 = (const float*)d_in[10];
    const float* CL_W2 = (const float*)d_in[11]; const float* CL_b2 = (const float*)d_in[12];
    const float* CL_W3 = (const float*)d_in[13]; const float* CL_b3 = (const float*)d_in[14];
    const float* L_Wih = (const float*)d_in[15]; const float* L_Whh = (const float*)d_in[16];
    const float* L_b   = (const float*)d_in[17];
    const float* C_Wih = (const float*)d_in[18]; const float* C_Whh = (const float*)d_in[19];
    const float* C_b   = (const float*)d_in[20];
    const float* V_W1 = (const float*)d_in[21]; const float* V_b1 = (const float*)d_in[22];
    const float* V_W2 = (const float*)d_in[23]; const float* V_b2 = (const float*)d_in[24];
    const float* V_W3 = (const float*)d_in[25]; const float* V_b3 = (const float*)d_in[26];
    float* out = (float*)d_out;

    char* ws = (char*)d_ws;
    size_t off = 0;
    auto alloc = [&](size_t bytes) -> void* {
        void* p = ws + off;
        off += (bytes + 255) & ~(size_t)255;
        return p;
    };
    const size_t NE = (size_t)NRP * EMB;
    short* HAh = (short*)alloc(NE * 2); short* HAl = (short*)alloc(NE * 2);
    short* HBh = (short*)alloc(NE * 2); short* HBl = (short*)alloc(NE * 2);
    float* CA = (float*)alloc(NE * 4);  float* CB = (float*)alloc(NE * 4);
    short* msgsH = (short*)alloc(NE * 2); short* msgsL = (short*)alloc(NE * 2);
    float* Xmsg = (float*)alloc(NE * 4);
    short* H1h = (short*)alloc((size_t)NRP * 416 * 2); short* H1l = (short*)alloc((size_t)NRP * 416 * 2);
    short* H2h = (short*)alloc((size_t)NRP * 224 * 2); short* H2l = (short*)alloc((size_t)NRP * 224 * 2);
    float* gates = (float*)alloc((size_t)NRP * 512 * 4);
    float* accum = (float*)alloc(256);
    // split/padded weights
    short* W1hL = (short*)alloc(448 * 128 * 2); short* W1lL = (short*)alloc(448 * 128 * 2);
    short* W1hC = (short*)alloc(448 * 128 * 2); short* W1lC = (short*)alloc(448 * 128 * 2);
    short* W2hL = (short*)alloc(256 * 416 * 2); short* W2lL = (short*)alloc(256 * 416 * 2);
    short* W2hC = (short*)alloc(256 * 416 * 2); short* W2lC = (short*)alloc(256 * 416 * 2);
    short* W3hL = (short*)alloc(128 * 224 * 2); short* W3lL = (short*)alloc(128 * 224 * 2);
    short* W3hC = (short*)alloc(128 * 224 * 2); short* W3lC = (short*)alloc(128 * 224 * 2);
    short* WihhL = (short*)alloc(512 * 128 * 2); short* WihlL = (short*)alloc(512 * 128 * 2);
    short* WhhhL = (short*)alloc(512 * 128 * 2); short* WhhlL = (short*)alloc(512 * 128 * 2);
    short* WihhC = (short*)alloc(512 * 128 * 2); short* WihlC = (short*)alloc(512 * 128 * 2);
    short* WhhhC = (short*)alloc(512 * 128 * 2); short* WhhlC = (short*)alloc(512 * 128 * 2);
    short* V1h = (short*)alloc(448 * 128 * 2); short* V1l = (short*)alloc(448 * 128 * 2);
    short* V2h = (short*)alloc(256 * 416 * 2); short* V2l = (short*)alloc(256 * 416 * 2);
    // CSR
    int* Lp   = (int*)alloc(4104 * 4);
    int* Tp   = (int*)alloc(8104 * 4);
    int* Lidx = (int*)alloc(1000000 * 4);
    int* Tidx = (int*)alloc(1000000 * 4);
    int* cnt2d = (int*)alloc((size_t)NCHUNK * NC * 4);
    int* cum2d = (int*)alloc((size_t)NCHUNK * NC * 4);
    int* cntL = (int*)alloc(4096 * 4);
    int* cntT = (int*)alloc(8192 * 4);
    (void)ws_size; (void)in_sizes; (void)n_in; (void)out_size;

    // --- CSR build ---
    count_rows_L<<<NL, 256, 0, stream>>>(M, cntL);
    scan_excl<<<1, 256, 0, stream>>>(cntL, Lp, NL);
    fill_L<<<NL, 256, 0, stream>>>(M, Lp, Lidx);
    {
        dim3 g((NC + 255) / 256, NCHUNK);
        count_T<<<g, 256, 0, stream>>>(M, cnt2d);
        colscan_T<<<(NC + 255) / 256, 256, 0, stream>>>(cnt2d, cum2d, cntT);
        scan_excl<<<1, 256, 0, stream>>>(cntT, Tp, NC);
        fill_T<<<g, 256, 0, stream>>>(M, Tp, cum2d, Tidx);
    }

    // --- weight split/pad ---
    auto sp = [&](const float* W, short* Wh, short* Wl, int r, int c, int pr, int pc) {
        split_pad<<<(pr * pc + 255) / 256, 256, 0, stream>>>(W, Wh, Wl, r, c, pr, pc);
    };
    sp(LC_W1, W1hL, W1lL, 400, 128, 448, 128);
    sp(CL_W1, W1hC, W1lC, 400, 128, 448, 128);
    sp(LC_W2, W2hL, W2lL, 200, 400, 256, 416);
    sp(CL_W2, W2hC, W2lC, 200, 400, 256, 416);
    sp(LC_W3, W3hL, W3lL, 128, 200, 128, 224);
    sp(CL_W3, W3hC, W3lC, 128, 200, 128, 224);
    sp(L_Wih, WihhL, WihlL, 512, 128, 512, 128);
    sp(L_Whh, WhhhL, WhhlL, 512, 128, 512, 128);
    sp(C_Wih, WihhC, WihlC, 512, 128, 512, 128);
    sp(C_Whh, WhhhC, WhhlC, 512, 128, 512, 128);
    sp(V_W1, V1h, V1l, 400, 128, 448, 128);
    sp(V_W2, V2h, V2l, 200, 400, 256, 416);

    const int nelem_blocks = (int)((NE + 255) / 256);
    init_states<<<nelem_blocks, 256, 0, stream>>>(L_init, C_init, HAh, HAl, CA, accum);

    // --- 30 message-passing steps ---
    short *Hch = HAh, *Hcl = HAl, *Hnh = HBh, *Hnl = HBl;
    float *Ccur = CA, *Cnxt = CB;
    for (int step = 0; step < TSTEPS; ++step) {
        mfma_gemm<128, false, true, true><<<dim3(7, 48), 256, 0, stream>>>(
            Hch, Hcl, nullptr, nullptr,
            W1hL, W1lL, W1hC, W1lC, nullptr, nullptr, nullptr, nullptr,
            LC_b1, CL_b1, H1h, H1l, nullptr, 400, 416);
        mfma_gemm<416, false, true, true><<<dim3(4, 48), 256, 0, stream>>>(
            H1h, H1l, nullptr, nullptr,
            W2hL, W2lL, W2hC, W2lC, nullptr, nullptr, nullptr, nullptr,
            LC_b2, CL_b2, H2h, H2l, nullptr, 200, 224);
        mfma_gemm<224, false, false, false><<<dim3(2, 48), 256, 0, stream>>>(
            H2h, H2l, nullptr, nullptr,
            W3hL, W3lL, W3hC, W3lC, nullptr, nullptr, nullptr, nullptr,
            LC_b3, CL_b3, nullptr, nullptr, Xmsg, 128, 128);
        spmm_kernel<<<(NRREAL + 1) / 2, 256, 0, stream>>>(Lp, Lidx, Tp, Tidx, Xmsg, msgsH, msgsL);
        mfma_gemm<128, true, false, false><<<dim3(8, 48), 256, 0, stream>>>(
            msgsH, msgsL, Hch, Hcl,
            WihhL, WihlL, WihhC, WihlC, WhhhL, WhhlL, WhhhC, WhhlC,
            L_b, C_b, nullptr, nullptr, gates, 512, 512);
        lstm_elem<<<nelem_blocks, 256, 0, stream>>>(gates, Ccur, Hnh, Hnl, Cnxt);
        short* th = Hch; Hch = Hnh; Hnh = th;
        short* tl = Hcl; Hcl = Hnl; Hnl = tl;
        float* tc = Ccur; Ccur = Cnxt; Cnxt = tc;
    }

    // --- vote MLP + logit (lit rows only: grid.y = 16) ---
    mfma_gemm<128, false, true, true><<<dim3(7, 16), 256, 0, stream>>>(
        Hch, Hcl, nullptr, nullptr,
        V1h, V1l, V1h, V1l, nullptr, nullptr, nullptr, nullptr,
        V_b1, V_b1, H1h, H1l, nullptr, 400, 416);
    mfma_gemm<416, false, true, true><<<dim3(4, 16), 256, 0, stream>>>(
        H1h, H1l, nullptr, nullptr,
        V2h, V2l, V2h, V2l, nullptr, nullptr, nullptr, nullptr,
        V_b2, V_b2, H2h, H2l, nullptr, 200, 224);
    vote_reduce<<<(NL + 3) / 4, 256, 0, stream>>>(H2h, H2l, V_W3, V_b3, accum);
    finalize_logit<<<1, 1, 0, stream>>>(accum, out);
}

// Round 3
// 4663.587 us; speedup vs baseline: 1.3386x; 1.0787x over previous
//
#include <hip/hip_runtime.h>

#define NL 4000
#define NC 8000
#define EMB 128
#define ROWC0 4096           // clause region start
#define NRP 12288            // padded total rows (96 x 128)
#define NRREAL (ROWC0 + NC)  // 12096 rows with data
#define TSTEPS 30
#define LCHUNK 80
#define NCHUNK 50

typedef __attribute__((ext_vector_type(8))) short bf16x8;
typedef __attribute__((ext_vector_type(4))) float f32x4;

__device__ __forceinline__ short f2bf(float x) {
    union { float f; unsigned u; } v; v.f = x;
    unsigned r = v.u + 0x7fffu + ((v.u >> 16) & 1u);
    return (short)(r >> 16);
}
__device__ __forceinline__ float bf2f(short s) {
    union { unsigned u; float f; } v; v.u = ((unsigned)(unsigned short)s) << 16;
    return v.f;
}

__device__ __forceinline__ void gload16(const void* g, void* l) {
    __builtin_amdgcn_global_load_lds(
        (const __attribute__((address_space(1))) unsigned int*)g,
        (__attribute__((address_space(3))) unsigned int*)l, 16, 0, 0);
}

// ---------------------------------------------------------------------------
// Split-bf16 MFMA GEMM, 2-stage pipelined double-buffered K-loop.
// Out[r][f] = act( sum_k A[r][k]*W[f][k] (+ phase2) + bias[f] )
// product = Ah*Wh + Ah*Wl + Al*Wh (fp32 acc, ~2^-17 rel err).
// Tile BM_ x BN_, waves (BM_/64)x(BN_/64), wave tile 64x64.
// LDS layout per 32-K chunk: row*32 shorts, 16B slots XOR-swizzled by
// slot ^ ((row>>1)&3); global source pre-swizzled, LDS dest linear (m173).
// Rows < ROWC0 use the L weight set, rows >= ROWC0 the C set.
// ---------------------------------------------------------------------------
template<int BM_, int BN_, int KS, bool TWOA, bool RELU, bool OUT_SPLIT>
__global__ __launch_bounds__((BM_/64)*(BN_/64)*64) void mfma_gemm(
    const short* __restrict__ A1h, const short* __restrict__ A1l,
    const short* __restrict__ A2h, const short* __restrict__ A2l,
    const short* __restrict__ W1hL, const short* __restrict__ W1lL,
    const short* __restrict__ W1hC, const short* __restrict__ W1lC,
    const short* __restrict__ W2hL, const short* __restrict__ W2lL,
    const short* __restrict__ W2hC, const short* __restrict__ W2lC,
    const float* __restrict__ biasL, const float* __restrict__ biasC,
    short* __restrict__ OutH, short* __restrict__ OutL, float* __restrict__ OutF,
    int Freal, int Fstore)
{
    constexpr int T = (BM_/64)*(BN_/64)*64;
    constexpr int KIT = KS / 32;
    constexpr int NIT = (TWOA ? 2 : 1) * KIT;

    __shared__ short sAh[2][BM_*32];
    __shared__ short sAl[2][BM_*32];
    __shared__ short sBh[2][BN_*32];
    __shared__ short sBl[2][BN_*32];

    const int row0 = blockIdx.y * BM_;
    const int c0 = blockIdx.x * BN_;
    const bool isC = (row0 >= ROWC0);
    const int t = threadIdx.x;
    const int lane = t & 63;
    const int w = t >> 6;
    constexpr int WCn = BN_/64;
    const int wr = w / WCn, wc = w % WCn;

    f32x4 acc[4][4] = {};

    auto stage = [&](int buf, int it) {
        const int ph = it / KIT;
        const int kc = (it - ph * KIT) * 32;
        const short *Ah, *Al, *Bh, *Bl;
        if (TWOA && ph) {
            Ah = A2h; Al = A2l;
            Bh = isC ? W2hC : W2hL; Bl = isC ? W2lC : W2lL;
        } else {
            Ah = A1h; Al = A1l;
            Bh = isC ? W1hC : W1hL; Bl = isC ? W1lC : W1lL;
        }
#pragma unroll
        for (int q = 0; q < BM_*4/T; ++q) {
            int c = q * T + t;
            int row = c >> 2, slot = c & 3;
            int gk = kc + ((slot ^ ((row >> 1) & 3)) << 3);
            size_t gi = (size_t)(row0 + row) * KS + gk;
            gload16(Ah + gi, &sAh[buf][c * 8]);
            gload16(Al + gi, &sAl[buf][c * 8]);
        }
#pragma unroll
        for (int q = 0; q < BN_*4/T; ++q) {
            int c = q * T + t;
            int row = c >> 2, slot = c & 3;
            int gk = kc + ((slot ^ ((row >> 1) & 3)) << 3);
            size_t gi = (size_t)(c0 + row) * KS + gk;
            gload16(Bh + gi, &sBh[buf][c * 8]);
            gload16(Bl + gi, &sBl[buf][c * 8]);
        }
    };

    // prologue
    stage(0, 0);
    asm volatile("s_waitcnt vmcnt(0)" ::: "memory");
    __syncthreads();

    int cur = 0;
    for (int it = 0; it < NIT; ++it) {
        if (it + 1 < NIT) stage(cur ^ 1, it + 1);   // loads fly under MFMAs

        bf16x8 af[4][2], bfr[4][2];
#pragma unroll
        for (int s = 0; s < 4; ++s) {
            int row = wr * 64 + s * 16 + (lane & 15);
            int slot = (lane >> 4) ^ ((row >> 1) & 3);
            int idx = row * 32 + slot * 8;
            af[s][0] = *(const bf16x8*)&sAh[cur][idx];
            af[s][1] = *(const bf16x8*)&sAl[cur][idx];
            int colr = wc * 64 + s * 16 + (lane & 15);
            int slotb = (lane >> 4) ^ ((colr >> 1) & 3);
            int idxb = colr * 32 + slotb * 8;
            bfr[s][0] = *(const bf16x8*)&sBh[cur][idxb];
            bfr[s][1] = *(const bf16x8*)&sBl[cur][idxb];
        }
#pragma unroll
        for (int s = 0; s < 4; ++s)
#pragma unroll
            for (int u = 0; u < 4; ++u) {
                acc[s][u] = __builtin_amdgcn_mfma_f32_16x16x32_bf16(af[s][0], bfr[u][0], acc[s][u], 0, 0, 0);
                acc[s][u] = __builtin_amdgcn_mfma_f32_16x16x32_bf16(af[s][0], bfr[u][1], acc[s][u], 0, 0, 0);
                acc[s][u] = __builtin_amdgcn_mfma_f32_16x16x32_bf16(af[s][1], bfr[u][0], acc[s][u], 0, 0, 0);
            }

        if (it + 1 < NIT) {
            asm volatile("s_waitcnt vmcnt(0)" ::: "memory");
            __syncthreads();
            cur ^= 1;
        }
    }

    // epilogue: C/D frag layout col=lane&15, row=(lane>>4)*4+j (m89)
#pragma unroll
    for (int u = 0; u < 4; ++u) {
        int col = c0 + wc * 64 + u * 16 + (lane & 15);
        if (col >= Fstore) continue;
        float bv = (col < Freal) ? (isC ? biasC[col] : biasL[col]) : 0.f;
#pragma unroll
        for (int s = 0; s < 4; ++s) {
#pragma unroll
            for (int j = 0; j < 4; ++j) {
                int row = row0 + wr * 64 + s * 16 + (lane >> 4) * 4 + j;
                float v = acc[s][u][j] + bv;
                if (RELU) v = fmaxf(v, 0.f);
                size_t oi = (size_t)row * Fstore + col;
                if (OUT_SPLIT) {
                    short h = f2bf(v);
                    OutH[oi] = h;
                    OutL[oi] = f2bf(v - bf2f(h));
                } else {
                    OutF[oi] = v;
                }
            }
        }
    }
}

// ---------------------------------------------------------------------------
// Weight prep: zero-padded split into hi/lo bf16.
// ---------------------------------------------------------------------------
__global__ __launch_bounds__(256) void split_pad(
    const float* __restrict__ W, short* __restrict__ Wh, short* __restrict__ Wl,
    int rows, int cols, int prows, int pcols)
{
    int i = blockIdx.x * 256 + threadIdx.x;
    if (i >= prows * pcols) return;
    int r = i / pcols, c = i - r * pcols;
    float v = (r < rows && c < cols) ? W[(size_t)r * cols + c] : 0.f;
    short h = f2bf(v);
    Wh[i] = h;
    Wl[i] = f2bf(v - bf2f(h));
}

// ---------------------------------------------------------------------------
// SpMM gather (fp32 in, split-bf16 out).
// ---------------------------------------------------------------------------
__global__ __launch_bounds__(256) void spmm_kernel(
    const int* __restrict__ Lp, const int* __restrict__ Li,
    const int* __restrict__ Tp, const int* __restrict__ Ti,
    const float* __restrict__ X, short* __restrict__ outH, short* __restrict__ outL)
{
    const int r = blockIdx.x * 2 + (threadIdx.x >> 7);
    const int col = threadIdx.x & 127;
    if (r >= NRREAL) return;
    float s = 0.f;
    if (r < NL) {
        int b = Lp[r], e = Lp[r + 1];
        int i = b;
        for (; i + 3 < e; i += 4) {
            s += X[(size_t)(ROWC0 + Li[i]) * EMB + col];
            s += X[(size_t)(ROWC0 + Li[i + 1]) * EMB + col];
            s += X[(size_t)(ROWC0 + Li[i + 2]) * EMB + col];
            s += X[(size_t)(ROWC0 + Li[i + 3]) * EMB + col];
        }
        for (; i < e; ++i) s += X[(size_t)(ROWC0 + Li[i]) * EMB + col];
    } else if (r >= ROWC0) {
        int c = r - ROWC0;
        int b = Tp[c], e = Tp[c + 1];
        int i = b;
        for (; i + 3 < e; i += 4) {
            s += X[(size_t)Ti[i] * EMB + col];
            s += X[(size_t)Ti[i + 1] * EMB + col];
            s += X[(size_t)Ti[i + 2] * EMB + col];
            s += X[(size_t)Ti[i + 3] * EMB + col];
        }
        for (; i < e; ++i) s += X[(size_t)Ti[i] * EMB + col];
    }
    size_t oi = (size_t)r * EMB + col;
    short h = f2bf(s);
    outH[oi] = h;
    outL[oi] = f2bf(s - bf2f(h));
}

// ---------------------------------------------------------------------------
// LSTM elementwise: gates [NRP][512] (i|f|g|o) -> split H, fp32 C.
// ---------------------------------------------------------------------------
__device__ __forceinline__ float sigf(float x) { return 1.f / (1.f + expf(-x)); }

__global__ __launch_bounds__(256) void lstm_elem(
    const float* __restrict__ gates, const float* __restrict__ Cold,
    short* __restrict__ Hh, short* __restrict__ Hl, float* __restrict__ Cnew)
{
    size_t idx = (size_t)blockIdx.x * 256 + threadIdx.x;
    if (idx >= (size_t)NRP * EMB) return;
    int r = (int)(idx >> 7);
    int e = (int)(idx & 127);
    const float* g = &gates[(size_t)r * 512];
    float gi = g[e], gf = g[e + 128], gg = g[e + 256], go = g[e + 384];
    float c2 = sigf(gf) * Cold[idx] + sigf(gi) * tanhf(gg);
    float h2 = sigf(go) * tanhf(c2);
    short h = f2bf(h2);
    Hh[idx] = h;
    Hl[idx] = f2bf(h2 - bf2f(h));
    Cnew[idx] = c2;
}

__global__ __launch_bounds__(256) void init_states(
    const float* __restrict__ Li, const float* __restrict__ Ci,
    short* __restrict__ Hh, short* __restrict__ Hl, float* __restrict__ C,
    float* __restrict__ accum)
{
    size_t idx = (size_t)blockIdx.x * 256 + threadIdx.x;
    if (idx >= (size_t)NRP * EMB) return;
    int r = (int)(idx >> 7);
    int e = (int)(idx & 127);
    float h = 0.f;
    if (r < NL) h = Li[e];
    else if (r >= ROWC0 && r < ROWC0 + NC) h = Ci[e];
    short hh = f2bf(h);
    Hh[idx] = hh;
    Hl[idx] = f2bf(h - bf2f(hh));
    C[idx] = 0.f;
    if (idx == 0) accum[0] = 0.f;
}

// ---------------------------------------------------------------------------
// CSR build (verified rounds 1-2)
// ---------------------------------------------------------------------------
__global__ __launch_bounds__(256) void count_rows_L(const float* __restrict__ M, int* __restrict__ cnt)
{
    int l = blockIdx.x, t = threadIdx.x;
    int c_ = 0;
    for (int c = t; c < NC; c += 256) c_ += (M[(size_t)l * NC + c] != 0.f) ? 1 : 0;
#pragma unroll
    for (int off = 32; off > 0; off >>= 1) c_ += __shfl_down(c_, off);
    __shared__ int w[4];
    if ((t & 63) == 0) w[t >> 6] = c_;
    __syncthreads();
    if (t == 0) cnt[l] = w[0] + w[1] + w[2] + w[3];
}

__global__ __launch_bounds__(256) void scan_excl(const int* __restrict__ in, int* __restrict__ out, int n)
{
    const int t = threadIdx.x;
    const int per = (n + 255) >> 8;
    __shared__ int part[256];
    int s = 0;
    const int start = t * per;
    for (int i = 0; i < per; ++i) { int idx = start + i; if (idx < n) s += in[idx]; }
    part[t] = s;
    __syncthreads();
    for (int off = 1; off < 256; off <<= 1) {
        int v = (t >= off) ? part[t - off] : 0;
        __syncthreads();
        part[t] += v;
        __syncthreads();
    }
    int run = (t == 0) ? 0 : part[t - 1];
    for (int i = 0; i < per; ++i) {
        int idx = start + i;
        if (idx < n) { out[idx] = run; run += in[idx]; }
    }
    if (t == 255) out[n] = part[255];
}

__global__ __launch_bounds__(256) void fill_L(const float* __restrict__ M,
                                              const int* __restrict__ Lp, int* __restrict__ Lidx)
{
    int l = blockIdx.x, t = threadIdx.x, lane = t & 63, wid = t >> 6;
    __shared__ int wcnt[4];
    __shared__ int base;
    if (t == 0) base = Lp[l];
    __syncthreads();
    for (int c0 = 0; c0 < NC; c0 += 256) {
        int c = c0 + t;
        bool p = (c < NC) && (M[(size_t)l * NC + c] != 0.f);
        unsigned long long m = __ballot(p);
        if (lane == 0) wcnt[wid] = (int)__popcll(m);
        __syncthreads();
        int off = base;
        for (int w = 0; w < wid; ++w) off += wcnt[w];
        int rank = (int)__popcll(m & ((1ull << lane) - 1ull));
        if (p) Lidx[off + rank] = c;
        __syncthreads();
        if (t == 0) base += wcnt[0] + wcnt[1] + wcnt[2] + wcnt[3];
        __syncthreads();
    }
}

__global__ __launch_bounds__(256) void count_T(const float* __restrict__ M, int* __restrict__ cnt2d)
{
    int s = blockIdx.y;
    int c = blockIdx.x * 256 + threadIdx.x;
    if (c >= NC) return;
    int n = 0;
    int l0 = s * LCHUNK, l1 = l0 + LCHUNK;
    for (int l = l0; l < l1; ++l) n += (M[(size_t)l * NC + c] != 0.f) ? 1 : 0;
    cnt2d[(size_t)s * NC + c] = n;
}

__global__ __launch_bounds__(256) void colscan_T(const int* __restrict__ cnt2d,
                                                 int* __restrict__ cum2d, int* __restrict__ cntT)
{
    int c = blockIdx.x * 256 + threadIdx.x;
    if (c >= NC) return;
    int run = 0;
    for (int s = 0; s < NCHUNK; ++s) {
        cum2d[(size_t)s * NC + c] = run;
        run += cnt2d[(size_t)s * NC + c];
    }
    cntT[c] = run;
}

__global__ __launch_bounds__(256) void fill_T(const float* __restrict__ M,
                                              const int* __restrict__ Tp, const int* __restrict__ cum2d,
                                              int* __restrict__ Tidx)
{
    int s = blockIdx.y;
    int c = blockIdx.x * 256 + threadIdx.x;
    if (c >= NC) return;
    int pos = Tp[c] + cum2d[(size_t)s * NC + c];
    int l0 = s * LCHUNK, l1 = l0 + LCHUNK;
    for (int l = l0; l < l1; ++l) {
        if (M[(size_t)l * NC + c] != 0.f) Tidx[pos++] = l;
    }
}

// ---------------------------------------------------------------------------
// Vote epilogue
// ---------------------------------------------------------------------------
__global__ __launch_bounds__(256) void vote_reduce(
    const short* __restrict__ H2h, const short* __restrict__ H2l,
    const float* __restrict__ W3, const float* __restrict__ b3, float* __restrict__ accum)
{
    int wid = threadIdx.x >> 6, lane = threadIdx.x & 63;
    int r = blockIdx.x * 4 + wid;
    float s = 0.f;
    if (r < NL) {
        const short* xh = &H2h[(size_t)r * 224];
        const short* xl = &H2l[(size_t)r * 224];
        for (int k = lane; k < 200; k += 64) s += (bf2f(xh[k]) + bf2f(xl[k])) * W3[k];
    }
#pragma unroll
    for (int off = 32; off > 0; off >>= 1) s += __shfl_down(s, off);
    if (lane == 0 && r < NL) {
        float v = 1.f / (1.f + expf(-(s + b3[0])));
        atomicAdd(accum, v);
    }
}

__global__ void finalize_logit(const float* __restrict__ accum, float* __restrict__ out)
{
    float avg = accum[0] / (float)NL;
    out[0] = logf(avg / (1.f - avg));
}

// ---------------------------------------------------------------------------
// Host launcher
// ---------------------------------------------------------------------------
extern "C" void kernel_launch(void* const* d_in, const int* in_sizes, int n_in,
                              void* d_out, int out_size, void* d_ws, size_t ws_size,
                              hipStream_t stream)
{
    const float* M      = (const float*)d_in[0];
    const float* L_init = (const float*)d_in[1];
    const float* C_init = (const float*)d_in[2];
    const float* LC_W1 = (const float*)d_in[3];  const float* LC_b1 = (const float*)d_in[4];
    const float* LC_W2 = (const float*)d_in[5];  const float* LC_b2 = (const float*)d_in[6];
    const float* LC_W3 = (const float*)d_in[7];  const float* LC_b3 = (const float*)d_in[8];
    const float* CL_W1 = (const float*)d_in[9];  const float* CL_b1 = (const float*)d_in[10];
    const float* CL_W2 = (const float*)d_in[11]; const float* CL_b2 = (const float*)d_in[12];
    const float* CL_W3 = (const float*)d_in[13]; const float* CL_b3 = (const float*)d_in[14];
    const float* L_Wih = (const float*)d_in[15]; const float* L_Whh = (const float*)d_in[16];
    const float* L_b   = (const float*)d_in[17];
    const float* C_Wih = (const float*)d_in[18]; const float* C_Whh = (const float*)d_in[19];
    const float* C_b   = (const float*)d_in[20];
    const float* V_W1 = (const float*)d_in[21]; const float* V_b1 = (const float*)d_in[22];
    const float* V_W2 = (const float*)d_in[23]; const float* V_b2 = (const float*)d_in[24];
    const float* V_W3 = (const float*)d_in[25]; const float* V_b3 = (const float*)d_in[26];
    float* out = (float*)d_out;

    char* ws = (char*)d_ws;
    size_t off = 0;
    auto alloc = [&](size_t bytes) -> void* {
        void* p = ws + off;
        off += (bytes + 255) & ~(size_t)255;
        return p;
    };
    const size_t NE = (size_t)NRP * EMB;
    short* HAh = (short*)alloc(NE * 2); short* HAl = (short*)alloc(NE * 2);
    short* HBh = (short*)alloc(NE * 2); short* HBl = (short*)alloc(NE * 2);
    float* CA = (float*)alloc(NE * 4);  float* CB = (float*)alloc(NE * 4);
    short* msgsH = (short*)alloc(NE * 2); short* msgsL = (short*)alloc(NE * 2);
    float* Xmsg = (float*)alloc(NE * 4);
    short* H1h = (short*)alloc((size_t)NRP * 416 * 2); short* H1l = (short*)alloc((size_t)NRP * 416 * 2);
    short* H2h = (short*)alloc((size_t)NRP * 224 * 2); short* H2l = (short*)alloc((size_t)NRP * 224 * 2);
    float* gates = (float*)alloc((size_t)NRP * 512 * 4);
    float* accum = (float*)alloc(256);
    // split/padded weights (rows padded to multiples of 128 for BN=128 tiles)
    short* W1hL = (short*)alloc(512 * 128 * 2); short* W1lL = (short*)alloc(512 * 128 * 2);
    short* W1hC = (short*)alloc(512 * 128 * 2); short* W1lC = (short*)alloc(512 * 128 * 2);
    short* W2hL = (short*)alloc(256 * 416 * 2); short* W2lL = (short*)alloc(256 * 416 * 2);
    short* W2hC = (short*)alloc(256 * 416 * 2); short* W2lC = (short*)alloc(256 * 416 * 2);
    short* W3hL = (short*)alloc(128 * 224 * 2); short* W3lL = (short*)alloc(128 * 224 * 2);
    short* W3hC = (short*)alloc(128 * 224 * 2); short* W3lC = (short*)alloc(128 * 224 * 2);
    short* WihhL = (short*)alloc(512 * 128 * 2); short* WihlL = (short*)alloc(512 * 128 * 2);
    short* WhhhL = (short*)alloc(512 * 128 * 2); short* WhhlL = (short*)alloc(512 * 128 * 2);
    short* WihhC = (short*)alloc(512 * 128 * 2); short* WihlC = (short*)alloc(512 * 128 * 2);
    short* WhhhC = (short*)alloc(512 * 128 * 2); short* WhhlC = (short*)alloc(512 * 128 * 2);
    short* V1h = (short*)alloc(512 * 128 * 2); short* V1l = (short*)alloc(512 * 128 * 2);
    short* V2h = (short*)alloc(256 * 416 * 2); short* V2l = (short*)alloc(256 * 416 * 2);
    // CSR
    int* Lp   = (int*)alloc(4104 * 4);
    int* Tp   = (int*)alloc(8104 * 4);
    int* Lidx = (int*)alloc(1000000 * 4);
    int* Tidx = (int*)alloc(1000000 * 4);
    int* cnt2d = (int*)alloc((size_t)NCHUNK * NC * 4);
    int* cum2d = (int*)alloc((size_t)NCHUNK * NC * 4);
    int* cntL = (int*)alloc(4096 * 4);
    int* cntT = (int*)alloc(8192 * 4);
    (void)ws_size; (void)in_sizes; (void)n_in; (void)out_size;

    // --- CSR build ---
    count_rows_L<<<NL, 256, 0, stream>>>(M, cntL);
    scan_excl<<<1, 256, 0, stream>>>(cntL, Lp, NL);
    fill_L<<<NL, 256, 0, stream>>>(M, Lp, Lidx);
    {
        dim3 g((NC + 255) / 256, NCHUNK);
        count_T<<<g, 256, 0, stream>>>(M, cnt2d);
        colscan_T<<<(NC + 255) / 256, 256, 0, stream>>>(cnt2d, cum2d, cntT);
        scan_excl<<<1, 256, 0, stream>>>(cntT, Tp, NC);
        fill_T<<<g, 256, 0, stream>>>(M, Tp, cum2d, Tidx);
    }

    // --- weight split/pad ---
    auto sp = [&](const float* W, short* Wh, short* Wl, int r, int c, int pr, int pc) {
        split_pad<<<(pr * pc + 255) / 256, 256, 0, stream>>>(W, Wh, Wl, r, c, pr, pc);
    };
    sp(LC_W1, W1hL, W1lL, 400, 128, 512, 128);
    sp(CL_W1, W1hC, W1lC, 400, 128, 512, 128);
    sp(LC_W2, W2hL, W2lL, 200, 400, 256, 416);
    sp(CL_W2, W2hC, W2lC, 200, 400, 256, 416);
    sp(LC_W3, W3hL, W3lL, 128, 200, 128, 224);
    sp(CL_W3, W3hC, W3lC, 128, 200, 128, 224);
    sp(L_Wih, WihhL, WihlL, 512, 128, 512, 128);
    sp(L_Whh, WhhhL, WhhlL, 512, 128, 512, 128);
    sp(C_Wih, WihhC, WihlC, 512, 128, 512, 128);
    sp(C_Whh, WhhhC, WhhlC, 512, 128, 512, 128);
    sp(V_W1, V1h, V1l, 400, 128, 512, 128);
    sp(V_W2, V2h, V2l, 200, 400, 256, 416);

    const int nelem_blocks = (int)((NE + 255) / 256);
    init_states<<<nelem_blocks, 256, 0, stream>>>(L_init, C_init, HAh, HAl, CA, accum);

    // --- 30 message-passing steps ---
    short *Hch = HAh, *Hcl = HAl, *Hnh = HBh, *Hnl = HBl;
    float *Ccur = CA, *Cnxt = CB;
    for (int step = 0; step < TSTEPS; ++step) {
        mfma_gemm<128, 128, 128, false, true, true><<<dim3(4, 96), 256, 0, stream>>>(
            Hch, Hcl, nullptr, nullptr,
            W1hL, W1lL, W1hC, W1lC, nullptr, nullptr, nullptr, nullptr,
            LC_b1, CL_b1, H1h, H1l, nullptr, 400, 416);
        mfma_gemm<128, 128, 416, false, true, true><<<dim3(2, 96), 256, 0, stream>>>(
            H1h, H1l, nullptr, nullptr,
            W2hL, W2lL, W2hC, W2lC, nullptr, nullptr, nullptr, nullptr,
            LC_b2, CL_b2, H2h, H2l, nullptr, 200, 224);
        mfma_gemm<64, 128, 224, false, false, false><<<dim3(1, 192), 128, 0, stream>>>(
            H2h, H2l, nullptr, nullptr,
            W3hL, W3lL, W3hC, W3lC, nullptr, nullptr, nullptr, nullptr,
            LC_b3, CL_b3, nullptr, nullptr, Xmsg, 128, 128);
        spmm_kernel<<<(NRREAL + 1) / 2, 256, 0, stream>>>(Lp, Lidx, Tp, Tidx, Xmsg, msgsH, msgsL);
        mfma_gemm<128, 128, 128, true, false, false><<<dim3(4, 96), 256, 0, stream>>>(
            msgsH, msgsL, Hch, Hcl,
            WihhL, WihlL, WihhC, WihlC, WhhhL, WhhlL, WhhhC, WhhlC,
            L_b, C_b, nullptr, nullptr, gates, 512, 512);
        lstm_elem<<<nelem_blocks, 256, 0, stream>>>(gates, Ccur, Hnh, Hnl, Cnxt);
        short* th = Hch; Hch = Hnh; Hnh = th;
        short* tl = Hcl; Hcl = Hnl; Hnl = tl;
        float* tc = Ccur; Ccur = Cnxt; Cnxt = tc;
    }

    // --- vote MLP + logit (lit rows only: 4096 rows = 32 tiles of 128) ---
    mfma_gemm<128, 128, 128, false, true, true><<<dim3(4, 32), 256, 0, stream>>>(
        Hch, Hcl, nullptr, nullptr,
        V1h, V1l, V1h, V1l, nullptr, nullptr, nullptr, nullptr,
        V_b1, V_b1, H1h, H1l, nullptr, 400, 416);
    mfma_gemm<128, 128, 416, false, true, true><<<dim3(2, 32), 256, 0, stream>>>(
        H1h, H1l, nullptr, nullptr,
        V2h, V2l, V2h, V2l, nullptr, nullptr, nullptr, nullptr,
        V_b2, V_b2, H2h, H2l, nullptr, 200, 224);
    vote_reduce<<<(NL + 3) / 4, 256, 0, stream>>>(H2h, H2l, V_W3, V_b3, accum);
    finalize_logit<<<1, 1, 0, stream>>>(accum, out);
}